// Round 1
// baseline (115.544 us; speedup 1.0000x reference)
//
#include <hip/hip_runtime.h>

// SelfAttentionPool, fused single kernel v5 (round 6).
// R1 49us -> R3 ~36.5 -> R4 ~31us -> v4 harness 110.6us total
// (~80us of that is two 256MiB harness poison-fills at 82% HBM; kernel ~28us
//  vs ~18us HBM floor -> gap is serialized per-block compute, not BW).
// v5: (a) no start barrier: deg counts + z-partials are per-wave-private,
//         each wave inits its own slice (same-wave LDS ordering), so the
//         x/edge global loads issue at cycle 0;
//     (b) dis[d] factored out of the edge scatter: z[c]=dis[c]*(a[c]+sum a[s])
//         -> 1600 fewer LDS reads + f64 muls per block;
//     (c) top-k rank 4x parallel: 4 threads/node scan 25 each, shfl_xor
//         combine, per-wave leader ballot -> cross-wave prefix via sh_mask7;
//     (d) sigmoid in f32 (__expf) -- drops the __ocml_exp_f64 blob + VGPRs.
// Numerics: z pipeline stays f64 (selection must match JAX f32 ranking).
//
// Output (float32): x_new (80000*128) | edge0 (E) | edge1 (E) | batch_new (80000)

#define NPG   100
#define EPG   1600
#define KNUM  80
#define FDIM  128
#define BT    512
#define NF4   (NPG * FDIM / 4)   // 3200 float4 of x per graph
#define NE4   (EPG / 4)          // 400 int4 per edge row
#define NCH   (NF4 / BT)         // 6 full chunks, remainder 128

__global__ __launch_bounds__(BT)
void sagpool_fused5(const float* __restrict__ x,
                    const int*   __restrict__ ei,
                    const float* __restrict__ theta,
                    float* __restrict__ out,
                    int E_total, int out_x_elems)
{
    const int g    = blockIdx.x;
    const int tid  = threadIdx.x;
    const int wave = tid >> 6;
    const int lane = tid & 63;
    const int base = g * NPG;

    __shared__ int4   sh_edge4[NE4];              // packed: s | (d<<16)
    __shared__ int    sh_cnt[8][NPG];             // per-wave private degree
    __shared__ double sh_s[NPG];
    __shared__ double sh_dis[NPG];
    __shared__ double sh_a[NPG];                  // s * dis
    __shared__ double sh_zp[8][NPG];              // per-wave private scatter
    __shared__ double sh_z[NPG];
    __shared__ unsigned long long sh_mask7[8];    // per-wave kept-leader masks
    __shared__ int    sh_newid[NPG];              // global out row, or -1
    __shared__ float  sh_scalen[NPG];             // sigmoid(z), by node
    int* sh_edge = (int*)sh_edge4;

    // per-wave private init -- no cross-wave race, no barrier needed:
    // a wave's own LDS writes complete before its own later atomics.
    {
        int*    cw = sh_cnt[wave];
        double* zw = sh_zp[wave];
        #pragma unroll
        for (int i = lane; i < NPG; i += 64) { cw[i] = 0; zw[i] = 0.0; }
    }

    // theta fragment: fixed per lane (col4 = lane&31), registers only
    const float4 th = ((const float4*)theta)[lane & 31];

    // ---- issue edge loads, then x-tile loads (stay in registers)
    const int4* src4 = (const int4*)(ei + (size_t)g * EPG);
    const int4* dst4 = (const int4*)(ei + (size_t)E_total + (size_t)g * EPG);
    const bool  hasE = tid < NE4;
    int4 es, ed;
    if (hasE) { es = src4[tid]; ed = dst4[tid]; }

    const float4* xb4 = (const float4*)(x + (size_t)base * FDIM);
    float4 v[NCH];
    #pragma unroll
    for (int i = 0; i < NCH; ++i) v[i] = xb4[i * BT + tid];
    const bool hasR = tid < (NF4 - NCH * BT);     // last 128 float4
    float4 vR;
    if (hasR) vR = xb4[NCH * BT + tid];

    // ---- edge pack + per-wave degree histogram (x loads still in flight)
    if (hasE) {
        int4 s4 = es, d4 = ed;
        s4.x -= base; s4.y -= base; s4.z -= base; s4.w -= base;
        d4.x -= base; d4.y -= base; d4.z -= base; d4.w -= base;
        int4 p; p.x = s4.x | (d4.x << 16); p.y = s4.y | (d4.y << 16);
                p.z = s4.z | (d4.z << 16); p.w = s4.w | (d4.w << 16);
        sh_edge4[tid] = p;
        int* cw = sh_cnt[wave];
        atomicAdd(&cw[s4.x], 1); atomicAdd(&cw[s4.y], 1);
        atomicAdd(&cw[s4.z], 1); atomicAdd(&cw[s4.w], 1);
    }

    // ---- dot: f64 partial + 32-lane xor-tree (32 consecutive idx = 1 row)
    #pragma unroll
    for (int i = 0; i < NCH; ++i) {
        double p = (double)v[i].x * th.x + (double)v[i].y * th.y
                 + (double)v[i].z * th.z + (double)v[i].w * th.w;
        #pragma unroll
        for (int m = 1; m <= 16; m <<= 1) p += __shfl_xor(p, m, 64);
        if ((lane & 31) == 0) sh_s[(i * BT + tid) >> 5] = p;
    }
    if (hasR) {
        double p = (double)vR.x * th.x + (double)vR.y * th.y
                 + (double)vR.z * th.z + (double)vR.w * th.w;
        #pragma unroll
        for (int m = 1; m <= 16; m <<= 1) p += __shfl_xor(p, m, 64);
        if ((lane & 31) == 0) sh_s[(NCH * BT + tid) >> 5] = p;
    }
    __syncthreads();                              // B2: edges, cnt, s ready

    if (tid < NPG) {
        int deg = 1 + sh_cnt[0][tid] + sh_cnt[1][tid] + sh_cnt[2][tid]
                    + sh_cnt[3][tid] + sh_cnt[4][tid] + sh_cnt[5][tid]
                    + sh_cnt[6][tid] + sh_cnt[7][tid];
        double dis = 1.0 / sqrt((double)deg);
        sh_dis[tid] = dis;
        sh_a[tid]   = sh_s[tid] * dis;
    }
    __syncthreads();                              // B3: dis/a ready

    // ---- z scatter: accumulate sum of a[s] per dst (dis[d] hoisted out)
    {
        double* zp = sh_zp[wave];
        for (int j = tid; j < EPG; j += BT) {
            int p = sh_edge[j];
            int s = p & 0xffff;
            int d = p >> 16;
            atomicAdd(&zp[d], sh_a[s]);
        }
    }
    __syncthreads();                              // B4: scatter done

    if (tid < NPG) {
        double zi = sh_a[tid]                     // self-loop term (x dis later)
                  + sh_zp[0][tid] + sh_zp[1][tid] + sh_zp[2][tid] + sh_zp[3][tid]
                  + sh_zp[4][tid] + sh_zp[5][tid] + sh_zp[6][tid] + sh_zp[7][tid];
        sh_z[tid] = zi * sh_dis[tid];
        sh_newid[tid] = -1;
    }
    __syncthreads();                              // B5: z ready

    // ---- top-k rank, 4 threads per node (25 scans each) + shfl combine
    const bool rk = tid < 4 * NPG;
    const int  n  = tid >> 2;
    int r = 0;
    double zn = 0.0;
    if (rk) {
        zn = sh_z[n];
        const int j0 = (tid & 3) * 25;
        for (int j = j0; j < j0 + 25; ++j) {
            double zj = sh_z[j];
            r += (int)((zj > zn) | ((zj == zn) & (j < n)));
        }
    }
    r += __shfl_xor(r, 1, 64);
    r += __shfl_xor(r, 2, 64);                    // all 4 lanes hold full rank
    const bool lead = rk && ((tid & 3) == 0) && (r < KNUM);
    unsigned long long m = __ballot(lead);        // leader bits at lanes 4k
    if (lane == 0) sh_mask7[wave] = m;
    __syncthreads();                              // B6a: masks ready

    if (lead) {
        int before = __popcll(m & ((1ull << lane) - 1ull));
        for (int w2 = 0; w2 < wave; ++w2) before += __popcll(sh_mask7[w2]);
        int row = g * KNUM + before;
        sh_newid[n]  = row;
        float zf = (float)zn;
        sh_scalen[n] = 1.0f / (1.0f + __expf(-zf));
        out[(size_t)out_x_elems + 2 * (size_t)E_total + row] = (float)g; // batch_new
    }
    __syncthreads();                              // B6: newid/scalen ready

    // ---- x_new straight from the register-resident tile (no re-read)
    float4* outx = (float4*)out;
    #pragma unroll
    for (int i = 0; i < NCH; ++i) {
        int idx = i * BT + tid;
        int row = idx >> 5;
        int nid = sh_newid[row];
        if (nid >= 0) {
            float sc = sh_scalen[row];
            float4 o;
            o.x = v[i].x * sc; o.y = v[i].y * sc;
            o.z = v[i].z * sc; o.w = v[i].w * sc;
            outx[(size_t)nid * 32 + (idx & 31)] = o;
        }
    }
    if (hasR) {
        int idx = NCH * BT + tid;
        int row = idx >> 5;
        int nid = sh_newid[row];
        if (nid >= 0) {
            float sc = sh_scalen[row];
            float4 o;
            o.x = vR.x * sc; o.y = vR.y * sc;
            o.z = vR.z * sc; o.w = vR.w * sc;
            outx[(size_t)nid * 32 + (idx & 31)] = o;
        }
    }

    // ---- edge relabel, float4 stores
    float* e0 = out + out_x_elems;
    float* e1 = e0 + E_total;
    if (hasE) {
        int4 p = sh_edge4[tid];
        float4 o0, o1;
        {
            int s = p.x & 0xffff, d = p.x >> 16;
            int a = sh_newid[s], b = sh_newid[d];
            bool vv = (a >= 0) && (b >= 0);
            o0.x = vv ? (float)a : -1.0f; o1.x = vv ? (float)b : -1.0f;
        }
        {
            int s = p.y & 0xffff, d = p.y >> 16;
            int a = sh_newid[s], b = sh_newid[d];
            bool vv = (a >= 0) && (b >= 0);
            o0.y = vv ? (float)a : -1.0f; o1.y = vv ? (float)b : -1.0f;
        }
        {
            int s = p.z & 0xffff, d = p.z >> 16;
            int a = sh_newid[s], b = sh_newid[d];
            bool vv = (a >= 0) && (b >= 0);
            o0.z = vv ? (float)a : -1.0f; o1.z = vv ? (float)b : -1.0f;
        }
        {
            int s = p.w & 0xffff, d = p.w >> 16;
            int a = sh_newid[s], b = sh_newid[d];
            bool vv = (a >= 0) && (b >= 0);
            o0.w = vv ? (float)a : -1.0f; o1.w = vv ? (float)b : -1.0f;
        }
        ((float4*)e0)[(size_t)g * NE4 + tid] = o0;
        ((float4*)e1)[(size_t)g * NE4 + tid] = o1;
    }
}

extern "C" void kernel_launch(void* const* d_in, const int* in_sizes, int n_in,
                              void* d_out, int out_size, void* d_ws, size_t ws_size,
                              hipStream_t stream)
{
    const float* x     = (const float*)d_in[0];
    const int*   ei    = (const int*)d_in[1];
    const float* theta = (const float*)d_in[3];
    float* out = (float*)d_out;

    const int N = in_sizes[0] / FDIM;        // 100000
    const int E = in_sizes[1] / 2;           // 1600000
    const int B = N / NPG;                   // 1000
    const int out_x_elems = B * KNUM * FDIM; // 10,240,000

    sagpool_fused5<<<dim3(B), dim3(BT), 0, stream>>>(x, ei, theta, out, E, out_x_elems);
}

// Round 2
// 114.288 us; speedup vs baseline: 1.0110x; 1.0110x over previous
//
#include <hip/hip_runtime.h>

// SelfAttentionPool, fused single kernel v6 (round 7).
// History: R4 ~31us kernel (110.6 total) -> v5 ~33us (115.5 total, regression
// vs prediction -> wrong term attacked). Fill dispatches (2x256MiB @82% HBM,
// ~82us) are harness-fixed; kernel HBM floor ~17.8us.
// Theory: all blocks co-resident -> grid marches in lockstep phases
// (load ~9.7us | compute C ~10us | store ~8.1us, serialized). Dominant C term
// = per-chunk f64 shuffle trees: 70 ds_bpermute_b32 issues/thread ~= 5.5us of
// LDS-pipe serialization per CU.
// v6: dot reduction restructured: streaming loop writes ONE f64 partial to
//     LDS (stride-33 padding, <=2-way conflicts) -- zero cross-lane ops;
//     after B2, 400 threads reduce 8 partials each + two 4-lane shfl_xor,
//     q==0 lane folds in deg/dis/a (same barrier count). LDS dot issues
//     ~560 -> ~110 per block. LDS 45.7KB -> 3 blocks/CU -> 768+232 blocks
//     gives mild generation pipelining (load/compute/store overlap).
// Numerics: z pipeline stays f64 (sum order changes at ~1e-16 rel, far below
// selection margins which exceed JAX's own f32 error).
//
// Output (float32): x_new (80000*128) | edge0 (E) | edge1 (E) | batch_new (80000)

#define NPG   100
#define EPG   1600
#define KNUM  80
#define FDIM  128
#define BT    512
#define NF4   (NPG * FDIM / 4)   // 3200 float4 of x per graph
#define NE4   (EPG / 4)          // 400 int4 per edge row
#define NCH   (NF4 / BT)         // 6 full chunks, remainder 128
#define PSTR  33                 // padded partial stride (doubles) per row

__global__ __launch_bounds__(BT)
void sagpool_fused6(const float* __restrict__ x,
                    const int*   __restrict__ ei,
                    const float* __restrict__ theta,
                    float* __restrict__ out,
                    int E_total, int out_x_elems)
{
    const int g    = blockIdx.x;
    const int tid  = threadIdx.x;
    const int wave = tid >> 6;
    const int lane = tid & 63;
    const int base = g * NPG;

    __shared__ int4   sh_edge4[NE4];              // packed: s | (d<<16)
    __shared__ int    sh_cnt[8][NPG];             // per-wave private degree
    __shared__ double sh_part[NPG * PSTR];        // dot partials, padded rows
    __shared__ double sh_dis[NPG];
    __shared__ double sh_a[NPG];                  // s * dis
    __shared__ double sh_zp[8][NPG];              // per-wave private scatter
    __shared__ double sh_z[NPG];
    __shared__ unsigned long long sh_mask7[8];    // per-wave kept-leader masks
    __shared__ int    sh_newid[NPG];              // global out row, or -1
    __shared__ float  sh_scalen[NPG];             // sigmoid(z), by node
    int* sh_edge = (int*)sh_edge4;

    // per-wave private init -- same-wave LDS ordering, no barrier needed
    {
        int*    cw = sh_cnt[wave];
        double* zw = sh_zp[wave];
        for (int i = lane; i < NPG; i += 64) { cw[i] = 0; zw[i] = 0.0; }
    }

    // theta fragment: fixed per lane (col4 = tid&31), registers only
    const float4 th = ((const float4*)theta)[lane & 31];

    // ---- issue edge loads, then x-tile loads (stay in registers)
    const int4* src4 = (const int4*)(ei + (size_t)g * EPG);
    const int4* dst4 = (const int4*)(ei + (size_t)E_total + (size_t)g * EPG);
    const bool  hasE = tid < NE4;
    int4 es, ed;
    if (hasE) { es = src4[tid]; ed = dst4[tid]; }

    const float4* xb4 = (const float4*)(x + (size_t)base * FDIM);
    float4 v[NCH];
    #pragma unroll
    for (int i = 0; i < NCH; ++i) v[i] = xb4[i * BT + tid];
    const bool hasR = tid < (NF4 - NCH * BT);     // last 128 float4
    float4 vR;
    if (hasR) vR = xb4[NCH * BT + tid];

    // ---- edge pack + per-wave degree histogram (x loads still in flight)
    if (hasE) {
        int4 s4 = es, d4 = ed;
        s4.x -= base; s4.y -= base; s4.z -= base; s4.w -= base;
        d4.x -= base; d4.y -= base; d4.z -= base; d4.w -= base;
        int4 p; p.x = s4.x | (d4.x << 16); p.y = s4.y | (d4.y << 16);
                p.z = s4.z | (d4.z << 16); p.w = s4.w | (d4.w << 16);
        sh_edge4[tid] = p;
        int* cw = sh_cnt[wave];
        atomicAdd(&cw[s4.x], 1); atomicAdd(&cw[s4.y], 1);
        atomicAdd(&cw[s4.z], 1); atomicAdd(&cw[s4.w], 1);
    }

    // ---- dot: one f64 partial per float4, straight to LDS (no cross-lane).
    // addr = row*33 + k = idx + (idx>>5)
    #pragma unroll
    for (int i = 0; i < NCH; ++i) {
        int idx = i * BT + tid;
        double p = (double)v[i].x * th.x + (double)v[i].y * th.y
                 + (double)v[i].z * th.z + (double)v[i].w * th.w;
        sh_part[idx + (idx >> 5)] = p;
    }
    if (hasR) {
        int idx = NCH * BT + tid;
        double p = (double)vR.x * th.x + (double)vR.y * th.y
                 + (double)vR.z * th.z + (double)vR.w * th.w;
        sh_part[idx + (idx >> 5)] = p;
    }
    __syncthreads();                              // B2: edges, cnt, partials

    // ---- reduce: 4 threads/node sum 8 partials + 4-lane shfl combine,
    //      leader folds in degree -> dis, a (replaces old B2->B3 phase)
    if (tid < 4 * NPG) {
        const int n = tid >> 2, q = tid & 3;
        const double* pr = sh_part + n * PSTR + q * 8;
        double s = ((pr[0] + pr[1]) + (pr[2] + pr[3]))
                 + ((pr[4] + pr[5]) + (pr[6] + pr[7]));
        s += __shfl_xor(s, 1, 64);
        s += __shfl_xor(s, 2, 64);
        if (q == 0) {
            int deg = 1 + sh_cnt[0][n] + sh_cnt[1][n] + sh_cnt[2][n]
                        + sh_cnt[3][n] + sh_cnt[4][n] + sh_cnt[5][n]
                        + sh_cnt[6][n] + sh_cnt[7][n];
            double dis = 1.0 / sqrt((double)deg);
            sh_dis[n] = dis;
            sh_a[n]   = s * dis;
        }
    }
    __syncthreads();                              // B3: dis/a ready

    // ---- z scatter: accumulate sum of a[s] per dst (dis[d] hoisted out)
    {
        double* zp = sh_zp[wave];
        for (int j = tid; j < EPG; j += BT) {
            int p = sh_edge[j];
            int s = p & 0xffff;
            int d = p >> 16;
            atomicAdd(&zp[d], sh_a[s]);
        }
    }
    __syncthreads();                              // B4: scatter done

    if (tid < NPG) {
        double zi = sh_a[tid]                     // self-loop term
                  + sh_zp[0][tid] + sh_zp[1][tid] + sh_zp[2][tid] + sh_zp[3][tid]
                  + sh_zp[4][tid] + sh_zp[5][tid] + sh_zp[6][tid] + sh_zp[7][tid];
        sh_z[tid] = zi * sh_dis[tid];
        sh_newid[tid] = -1;
    }
    __syncthreads();                              // B5: z ready

    // ---- top-k rank, 4 threads per node (25 scans each) + shfl combine
    const bool rk = tid < 4 * NPG;
    const int  n  = tid >> 2;
    int r = 0;
    double zn = 0.0;
    if (rk) {
        zn = sh_z[n];
        const int j0 = (tid & 3) * 25;
        for (int j = j0; j < j0 + 25; ++j) {
            double zj = sh_z[j];
            r += (int)((zj > zn) | ((zj == zn) & (j < n)));
        }
    }
    r += __shfl_xor(r, 1, 64);
    r += __shfl_xor(r, 2, 64);                    // all 4 lanes hold full rank
    const bool lead = rk && ((tid & 3) == 0) && (r < KNUM);
    unsigned long long m = __ballot(lead);        // leader bits at lanes 4k
    if (lane == 0) sh_mask7[wave] = m;
    __syncthreads();                              // B6a: masks ready

    if (lead) {
        int before = __popcll(m & ((1ull << lane) - 1ull));
        for (int w2 = 0; w2 < wave; ++w2) before += __popcll(sh_mask7[w2]);
        int row = g * KNUM + before;
        sh_newid[n]  = row;
        float zf = (float)zn;
        sh_scalen[n] = 1.0f / (1.0f + __expf(-zf));
        out[(size_t)out_x_elems + 2 * (size_t)E_total + row] = (float)g; // batch_new
    }
    __syncthreads();                              // B6: newid/scalen ready

    // ---- x_new straight from the register-resident tile (no re-read)
    float4* outx = (float4*)out;
    #pragma unroll
    for (int i = 0; i < NCH; ++i) {
        int idx = i * BT + tid;
        int row = idx >> 5;
        int nid = sh_newid[row];
        if (nid >= 0) {
            float sc = sh_scalen[row];
            float4 o;
            o.x = v[i].x * sc; o.y = v[i].y * sc;
            o.z = v[i].z * sc; o.w = v[i].w * sc;
            outx[(size_t)nid * 32 + (idx & 31)] = o;
        }
    }
    if (hasR) {
        int idx = NCH * BT + tid;
        int row = idx >> 5;
        int nid = sh_newid[row];
        if (nid >= 0) {
            float sc = sh_scalen[row];
            float4 o;
            o.x = vR.x * sc; o.y = vR.y * sc;
            o.z = vR.z * sc; o.w = vR.w * sc;
            outx[(size_t)nid * 32 + (idx & 31)] = o;
        }
    }

    // ---- edge relabel, float4 stores
    float* e0 = out + out_x_elems;
    float* e1 = e0 + E_total;
    if (hasE) {
        int4 p = sh_edge4[tid];
        float4 o0, o1;
        {
            int s = p.x & 0xffff, d = p.x >> 16;
            int a = sh_newid[s], b = sh_newid[d];
            bool vv = (a >= 0) && (b >= 0);
            o0.x = vv ? (float)a : -1.0f; o1.x = vv ? (float)b : -1.0f;
        }
        {
            int s = p.y & 0xffff, d = p.y >> 16;
            int a = sh_newid[s], b = sh_newid[d];
            bool vv = (a >= 0) && (b >= 0);
            o0.y = vv ? (float)a : -1.0f; o1.y = vv ? (float)b : -1.0f;
        }
        {
            int s = p.z & 0xffff, d = p.z >> 16;
            int a = sh_newid[s], b = sh_newid[d];
            bool vv = (a >= 0) && (b >= 0);
            o0.z = vv ? (float)a : -1.0f; o1.z = vv ? (float)b : -1.0f;
        }
        {
            int s = p.w & 0xffff, d = p.w >> 16;
            int a = sh_newid[s], b = sh_newid[d];
            bool vv = (a >= 0) && (b >= 0);
            o0.w = vv ? (float)a : -1.0f; o1.w = vv ? (float)b : -1.0f;
        }
        ((float4*)e0)[(size_t)g * NE4 + tid] = o0;
        ((float4*)e1)[(size_t)g * NE4 + tid] = o1;
    }
}

extern "C" void kernel_launch(void* const* d_in, const int* in_sizes, int n_in,
                              void* d_out, int out_size, void* d_ws, size_t ws_size,
                              hipStream_t stream)
{
    const float* x     = (const float*)d_in[0];
    const int*   ei    = (const int*)d_in[1];
    const float* theta = (const float*)d_in[3];
    float* out = (float*)d_out;

    const int N = in_sizes[0] / FDIM;        // 100000
    const int E = in_sizes[1] / 2;           // 1600000
    const int B = N / NPG;                   // 1000
    const int out_x_elems = B * KNUM * FDIM; // 10,240,000

    sagpool_fused6<<<dim3(B), dim3(BT), 0, stream>>>(x, ei, theta, out, E, out_x_elems);
}